// Round 13
// baseline (161.970 us; speedup 1.0000x reference)
//
#include <hip/hip_runtime.h>

typedef unsigned short u16;
typedef unsigned int u32;

typedef __bf16 bf16x8 __attribute__((ext_vector_type(8)));
typedef _Float16 f16x8 __attribute__((ext_vector_type(8)));
typedef float f32x4 __attribute__((ext_vector_type(4)));
typedef float f32x16 __attribute__((ext_vector_type(16)));
typedef u32 u32x4 __attribute__((ext_vector_type(4)));

typedef __attribute__((address_space(1))) u32 as1_u32;
typedef __attribute__((address_space(3))) u32 as3_u32;

#define EKF 0.18033688011112042f  // 0.125 * log2(e), folded into Q at GEMM1

__device__ __forceinline__ u16 f2bf(float x) {
  u32 u = __float_as_uint(x);
  u = u + 0x7fffu + ((u >> 16) & 1u);   // RNE
  return (u16)(u >> 16);
}
__device__ __forceinline__ u32 pack2(float a, float b) {
  return (u32)f2bf(a) | ((u32)f2bf(b) << 16);
}
__device__ __forceinline__ u32 pkf16(float a, float b) {
  return __builtin_bit_cast(u32, __builtin_amdgcn_cvt_pkrtz(a, b));
}
__device__ __forceinline__ u16 f2h(float a) {
  return (u16)(pkf16(a, a) & 0xffffu);
}
__device__ __forceinline__ void gld_lds16(const u16* g, const u16* l) {
  __builtin_amdgcn_global_load_lds((const as1_u32*)g, (as3_u32*)l, 16, 0, 0);
}

// ---------------- fused prepass: x cast + both weight transposes ----------------
__global__ __launch_bounds__(256) void prepass_kernel(const float* __restrict__ x,
                                                      const float* __restrict__ w_qkv,
                                                      const float* __restrict__ w_out,
                                                      u16* __restrict__ xb,
                                                      u16* __restrict__ wqkvT,
                                                      u16* __restrict__ woutT) {
  __shared__ float tile[64][65];
  int bid = blockIdx.x;
  int t = threadIdx.x;
  if (bid < 4096) {
    int i = bid * 256 + t;
    float4 v = ((const float4*)x)[i];
    uint2 r;
    r.x = pack2(v.x, v.y);
    r.y = pack2(v.z, v.w);
    ((uint2*)xb)[i] = r;
    return;
  }
  const float* W;
  u16* WT;
  int K, N, bx, by;
  if (bid < 4096 + 768) {
    int b2 = bid - 4096;
    W = w_qkv; WT = wqkvT; K = 1024; N = 3072; bx = b2 & 15; by = b2 >> 4;
  } else {
    int b2 = bid - 4864;
    W = w_out; WT = woutT; K = 1024; N = 1024; bx = b2 & 15; by = b2 >> 4;
  }
  int k0 = bx * 64, n0 = by * 64;
  int r = t >> 4, c4 = (t & 15) * 4;
#pragma unroll
  for (int i = 0; i < 4; ++i) {
    int row = r + i * 16;
    float4 v = *(const float4*)&W[(size_t)(k0 + row) * N + n0 + c4];
    tile[row][c4 + 0] = v.x; tile[row][c4 + 1] = v.y;
    tile[row][c4 + 2] = v.z; tile[row][c4 + 3] = v.w;
  }
  __syncthreads();
#pragma unroll
  for (int i = 0; i < 4; ++i) {
    int n = r + i * 16;
    uint2 o;
    o.x = pack2(tile[c4 + 0][n], tile[c4 + 1][n]);
    o.y = pack2(tile[c4 + 2][n], tile[c4 + 3][n]);
    *(uint2*)&WT[(size_t)(n0 + n) * K + k0 + c4] = o;
  }
}

// ---------------- QKV GEMM v3 (unchanged from R11): 128x192, 512 blocks ----------
__global__ __launch_bounds__(512, 4) void gemm_qkv128_kernel(const u16* __restrict__ A,
                                                             const u16* __restrict__ BT,
                                                             u16* __restrict__ QK,
                                                             u16* __restrict__ VT) {
  __shared__ __attribute__((aligned(16))) u16 smem[40960];  // 80 KiB: 2 x (8192 + 12288)
  const int tid = threadIdx.x;
  const int wave = tid >> 6;
  const int lane = tid & 63;
  const int lr = lane & 15;
  const int kg = lane >> 4;
  const int l7 = lr & 7;
  const int wr = wave >> 2;   // 0..1 : M half (64 rows)
  const int wc = wave & 3;    // 0..3 : N quarter (48 cols)

  const int b = blockIdx.x;
  const int xcd = b & 7, loc = b >> 3;            // loc 0..63
  const int bm = (xcd * 4 + (loc >> 4)) * 128;    // 32 M-tiles, 4 per XCD
  const int bn = (loc & 15) * 192;                // 16 N-tiles

  const int srow = tid >> 3;                      // 0..63
  const int scg = ((tid & 7) ^ (srow & 7)) * 8;   // swizzled source col (u16)
  const u16* pa = A + (size_t)(bm + srow) * 1024 + scg;
  const u16* pb = BT + (size_t)(bn + srow) * 1024 + scg;
  const u32 lw = (u32)wave * 512;

  f32x4 acc[4][3];
#pragma unroll
  for (int i = 0; i < 4; ++i)
#pragma unroll
    for (int j = 0; j < 3; ++j) {
      f32x4 z = {0.f, 0.f, 0.f, 0.f};
      acc[i][j] = z;
    }

  {  // prologue: stage tile 0 into buffer 0
    u16* dA = (u16*)smem;
    u16* dB = (u16*)smem + 8192;
#pragma unroll
    for (int i = 0; i < 2; ++i) gld_lds16(pa + (size_t)(i * 64) * 1024, dA + lw + i * 4096);
#pragma unroll
    for (int i = 0; i < 3; ++i) gld_lds16(pb + (size_t)(i * 64) * 1024, dB + lw + i * 4096);
  }

  for (int t = 0; t < 16; ++t) {
    __syncthreads();
    const u16* bA = smem + (t & 1) * 20480;
    const u16* bB = bA + 8192;
    if (t + 1 < 16) {
      u16* dA = (u16*)smem + ((t + 1) & 1) * 20480;
      u16* dB = dA + 8192;
      const int k1 = (t + 1) * 64;
#pragma unroll
      for (int i = 0; i < 2; ++i) gld_lds16(pa + (size_t)(i * 64) * 1024 + k1, dA + lw + i * 4096);
#pragma unroll
      for (int i = 0; i < 3; ++i) gld_lds16(pb + (size_t)(i * 64) * 1024 + k1, dB + lw + i * 4096);
    }
#pragma unroll
    for (int kk = 0; kk < 2; ++kk) {
      const int ch = ((kk * 4 + kg) ^ l7) * 8;
      bf16x8 af[4], bfr[3];
#pragma unroll
      for (int mi = 0; mi < 4; ++mi)
        af[mi] = *(const bf16x8*)(bA + (wr * 64 + mi * 16 + lr) * 64 + ch);
#pragma unroll
      for (int ni = 0; ni < 3; ++ni)
        bfr[ni] = *(const bf16x8*)(bB + (wc * 48 + ni * 16 + lr) * 64 + ch);
      __builtin_amdgcn_s_setprio(1);
#pragma unroll
      for (int mi = 0; mi < 4; ++mi)
#pragma unroll
        for (int ni = 0; ni < 3; ++ni)
          acc[mi][ni] = __builtin_amdgcn_mfma_f32_16x16x32_bf16(bfr[ni], af[mi], acc[mi][ni], 0, 0, 0);
      __builtin_amdgcn_s_setprio(0);
    }
  }

  __syncthreads();
#pragma unroll
  for (int i = 0; i < 4; ++i)
#pragma unroll
    for (int ni = 0; ni < 3; ++ni) {
      const int coff = wc * 48 + ni * 16 + kg * 4;  // col-in-tile
      const int cglob = bn + coff;
      f32x4 a = acc[i][ni];
      if (cglob >= 2048) {
        int r = bm + wr * 64 + i * 16 + lr;
        int cc = cglob - 2048;
        int bh2 = (r >> 11) * 16 + (cc >> 6);
        int j = r & 2047;
        u16* vrow = VT + ((size_t)bh2 * 64 + (cc & 63)) * 2048 + j;
#pragma unroll
        for (int rr = 0; rr < 4; ++rr) vrow[(size_t)rr * 2048] = f2h(a[rr]);
      } else {
        float scale = (cglob < 1024) ? EKF : 1.0f;
        int row = wr * 64 + i * 16 + lr;    // 0..127
        int chunk = coff >> 2;              // 0..47
        u32 off = (u32)row * 192 + (u32)((chunk ^ (row & 6)) << 2);
        *(uint2*)((u16*)smem + off) =
            make_uint2(pack2(a[0] * scale, a[1] * scale), pack2(a[2] * scale, a[3] * scale));
      }
    }
  __syncthreads();
  if (bn < 2048) {
#pragma unroll
    for (int i2 = 0; i2 < 8; ++i2) {
      int row = i2 * 16 + (tid >> 5);
      int lc = tid & 31;
      if (lc < 24 && bn + lc * 8 < 2048) {
        uint4 v = *(const uint4*)((const u16*)smem + (u32)row * 192 +
                                  (u32)(((2 * lc) ^ (row & 6)) * 4));
        *(uint4*)(QK + (size_t)(bm + row) * 2048 + bn + lc * 8) = v;
      }
    }
  }
}

// ---------------- out-proj GEMM (unchanged from R5) ----------------
__global__ __launch_bounds__(256, 2) void gemm_out_kernel(const u16* __restrict__ A,
                                                          const u16* __restrict__ BT,
                                                          float* __restrict__ C) {
  __shared__ __attribute__((aligned(16))) u16 smem[2][12288];  // A 64x64 + B 128x64 per buf
  const int tid = threadIdx.x;
  const int wave = tid >> 6;
  const int lane = tid & 63;
  const int lr = lane & 15;
  const int kg = lane >> 4;
  const int lr7 = lr & 7;
  const int wm = (wave >> 1) * 32;  // M half (32 rows per wave)
  const int wn = (wave & 1) * 64;   // N half (64 cols per wave)

  const int b = blockIdx.x;
  const int xcd = b & 7, loc = b >> 3;           // loc 0..63
  const int bm = (xcd * 8 + (loc >> 3)) * 64;    // 64 M-panels, 8 per XCD
  const int bn = (loc & 7) * 128;                // 8 N-tiles

  const int sr = tid >> 3;                        // 0..31
  const int scg = ((tid & 7) ^ (sr & 7)) * 8;     // swizzled source col (u16)
  const u16* pa = A + (size_t)(bm + sr) * 1024 + scg;
  const u16* pb = BT + (size_t)(bn + sr) * 1024 + scg;
  const u32 lw = (u32)wave * 512;

  f32x4 acc[2][4];
#pragma unroll
  for (int i = 0; i < 2; ++i)
#pragma unroll
    for (int j = 0; j < 4; ++j) {
      f32x4 z = {0.f, 0.f, 0.f, 0.f};
      acc[i][j] = z;
    }

  {  // prologue: stage tile 0 into buffer 0
    u16* dA = smem[0];
    u16* dB = smem[0] + 4096;
#pragma unroll
    for (int i = 0; i < 2; ++i) gld_lds16(pa + (size_t)(i * 32) * 1024, dA + lw + i * 2048);
#pragma unroll
    for (int i = 0; i < 4; ++i) gld_lds16(pb + (size_t)(i * 32) * 1024, dB + lw + i * 2048);
  }

  for (int t = 0; t < 16; ++t) {
    __syncthreads();  // tile t's loads complete
    const u16* bA = smem[t & 1];
    const u16* bB = bA + 4096;
    if (t + 1 < 16) {  // issue next tile with a full compute-phase of lead
      u16* dA = smem[(t + 1) & 1];
      u16* dB = dA + 4096;
      const int k1 = (t + 1) * 64;
#pragma unroll
      for (int i = 0; i < 2; ++i) gld_lds16(pa + (size_t)(i * 32) * 1024 + k1, dA + lw + i * 2048);
#pragma unroll
      for (int i = 0; i < 4; ++i) gld_lds16(pb + (size_t)(i * 32) * 1024 + k1, dB + lw + i * 2048);
    }
#pragma unroll
    for (int kk = 0; kk < 2; ++kk) {
      const int ch = ((kk * 4 + kg) ^ lr7) * 8;
      bf16x8 af[2], bfr[4];
#pragma unroll
      for (int mi = 0; mi < 2; ++mi)
        af[mi] = *(const bf16x8*)(bA + (wm + mi * 16 + lr) * 64 + ch);
#pragma unroll
      for (int ni = 0; ni < 4; ++ni)
        bfr[ni] = *(const bf16x8*)(bB + (wn + ni * 16 + lr) * 64 + ch);
      __builtin_amdgcn_s_setprio(1);
#pragma unroll
      for (int mi = 0; mi < 2; ++mi)
#pragma unroll
        for (int ni = 0; ni < 4; ++ni)
          acc[mi][ni] = __builtin_amdgcn_mfma_f32_16x16x32_bf16(bfr[ni], af[mi], acc[mi][ni], 0, 0, 0);
      __builtin_amdgcn_s_setprio(0);
    }
  }

  // epilogue: stage fp32 [64][64] col-halves through LDS, coalesced float4 out
  float* buf = (float*)smem;
#pragma unroll
  for (int hc = 0; hc < 2; ++hc) {
    __syncthreads();
    if ((wave & 1) == hc) {
#pragma unroll
      for (int mi = 0; mi < 2; ++mi)
#pragma unroll
        for (int ni = 0; ni < 4; ++ni) {
          int row = wm + mi * 16 + lr;                 // 0..63 (two waves cover all)
          int cp = ((ni * 4 + kg) ^ lr) * 4;           // 16-chunk swizzle, key lr
          *(f32x4*)(buf + row * 64 + cp) = acc[mi][ni];
        }
    }
    __syncthreads();
#pragma unroll
    for (int i = 0; i < 4; ++i) {
      int row = i * 16 + (tid >> 4);
      int lc = tid & 15;
      float4 v = *(const float4*)(buf + row * 64 + ((lc ^ (row & 15)) * 4));
      *(float4*)(C + (size_t)(bm + row) * 1024 + bn + hc * 64 + lc * 4) = v;
    }
  }
}

// ---------------- MFMA flash attention v15: v14 + balanced qi map + diag branch ---
// (1) Stride-256-balanced (qi,bh) map preserving XCD locality: idx = k*256 + c,
//     w = c>>5: qi = {31-w, w, 16+w, 15-w}[k], bh = (c&7)*4 + ((c>>3)&3).
//     For EVERY c the four co-resident stride-256 siblings sum to 66 rounds
//     (heavy-first gave per-CU sums 52..80 -> ~20% makespan tail). Bijective;
//     idx%8 = c&7 -> still 4 bh per XCD (2 MB K/V in L2, same as v14).
// (2) Causal-mask VALU (16 cmp + 16 cndmask) hoisted under a wave-uniform
//     if(diag): 31/33 rounds run the plain exp2 path.
__global__ __launch_bounds__(256, 4) void attn_mfma_kernel(const u16* __restrict__ qk,
                                                           const u16* __restrict__ vt,
                                                           u16* __restrict__ out) {
  __shared__ __attribute__((aligned(16))) u16 sK[2][64 * 64];  // [j][d] swizzled
  __shared__ __attribute__((aligned(16))) u16 sV[2][64 * 64];  // [d][j] swizzled

  const int tid = threadIdx.x;
  const int wave = tid >> 6;
  const int lane = tid & 63;
  const int l31 = lane & 31;
  const int hi = lane >> 5;
  const int qh = wave & 1;   // q half (32 rows of the 64-q tile)
  const int jh = wave >> 1;  // j half (32 cols of each 64-j tile)

  const int idx = blockIdx.x;
  const int kq = idx >> 8;       // 0..3
  const int ci = idx & 255;
  const int w = ci >> 5;         // 0..7
  const int qi = (kq == 0) ? (31 - w) : (kq == 1) ? w : (kq == 2) ? (16 + w) : (15 - w);
  const int bh = (ci & 7) * 4 + ((ci >> 3) & 3);  // XCD-local bh grouping
  const int b = bh >> 4, h = bh & 15;
  const int q0 = qi * 64;

  const u16* qbase = qk + (size_t)b * 2048 * 2048 + h * 64;
  const u16* kbase = qbase + 1024;
  const u16* vbase = vt + (size_t)bh * 64 * 2048;
  u16* obase = out + (size_t)b * 2048 * 1024 + h * 64;

  const int sra = wave * 16 + (lane >> 3);
  const int srb = sra + 8;
  const int sc = lane & 7;
  const u32 koffA = (u32)sra * 2048 + (u32)((sc ^ (sra & 7)) * 8);
  const u32 koffB = (u32)srb * 2048 + (u32)((sc ^ (srb & 7)) * 8);
  const u32 ldsA = (wave * 2 + 0) * 512;
  const u32 ldsB = (wave * 2 + 1) * 512;

  const int qcol = q0 + qh * 32 + l31;
  bf16x8 qf[4];
  {
    const u16* qrow = qbase + (size_t)qcol * 2048;
#pragma unroll
    for (int s = 0; s < 4; ++s) qf[s] = *(const bf16x8*)(qrow + s * 16 + hi * 8);
  }

  f32x16 oacc[2];
#pragma unroll
  for (int i = 0; i < 16; ++i) { oacc[0][i] = 0.f; oacc[1][i] = 0.f; }
  float ls = 0.f;

  const int nrounds = qi + 1;
  gld_lds16(kbase + koffA, sK[0] + ldsA);
  gld_lds16(kbase + koffB, sK[0] + ldsB);
  gld_lds16(vbase + koffA, sV[0] + ldsA);
  gld_lds16(vbase + koffB, sV[0] + ldsB);
  __syncthreads();

  for (int t = 0; t < nrounds; ++t) {
    if (t + 1 < nrounds) {
      int j1 = (t + 1) * 64;
      u16* dK = sK[(t + 1) & 1];
      u16* dV = sV[(t + 1) & 1];
      gld_lds16(kbase + (size_t)j1 * 2048 + koffA, dK + ldsA);
      gld_lds16(kbase + (size_t)j1 * 2048 + koffB, dK + ldsB);
      gld_lds16(vbase + j1 + koffA, dV + ldsA);
      gld_lds16(vbase + j1 + koffB, dV + ldsB);
    }
    const u16* sKb = sK[t & 1];
    const u16* sVb = sV[t & 1];
    const bool diag = (t == qi);

    f32x16 c;
#pragma unroll
    for (int i = 0; i < 16; ++i) c[i] = 0.f;
#pragma unroll
    for (int s = 0; s < 4; ++s) {
      const u32 row = (u32)(jh * 32 + l31);
      bf16x8 kf = *(const bf16x8*)(sKb + row * 64 + (((2 * s + hi) ^ (row & 7)) * 8));
      c = __builtin_amdgcn_mfma_f32_32x32x16_bf16(kf, qf[s], c, 0, 0, 0);
    }
    float p[16];
    if (diag) {  // wave-uniform branch: mask VALU only on the diagonal round
      const int qrel = qh * 32 + l31;
#pragma unroll
      for (int r = 0; r < 16; ++r) {
        int joff = jh * 32 + (r & 3) + 8 * (r >> 2) + 4 * hi;
        float e = exp2f(c[r]);
        p[r] = (joff <= qrel) ? e : 0.f;
      }
    } else {
#pragma unroll
      for (int r = 0; r < 16; ++r) p[r] = exp2f(c[r]);
    }
    {
      float s0 = (p[0] + p[1]) + (p[2] + p[3]);
      float s1 = (p[4] + p[5]) + (p[6] + p[7]);
      float s2 = (p[8] + p[9]) + (p[10] + p[11]);
      float s3 = (p[12] + p[13]) + (p[14] + p[15]);
      ls += (s0 + s1) + (s2 + s3);
    }
    u32 c01 = pkf16(p[0], p[1]),   c23 = pkf16(p[2], p[3]);
    u32 c45 = pkf16(p[4], p[5]),   c67 = pkf16(p[6], p[7]);
    u32 c89 = pkf16(p[8], p[9]),   cab = pkf16(p[10], p[11]);
    u32 ccd = pkf16(p[12], p[13]), cef = pkf16(p[14], p[15]);
    asm volatile("v_permlane32_swap_b32 %0, %1" : "+v"(c01), "+v"(c45));
    asm volatile("v_permlane32_swap_b32 %0, %1" : "+v"(c23), "+v"(c67));
    asm volatile("v_permlane32_swap_b32 %0, %1" : "+v"(c89), "+v"(ccd));
    asm volatile("v_permlane32_swap_b32 %0, %1" : "+v"(cab), "+v"(cef));
    u32x4 w0 = {c01, c23, c45, c67};
    u32x4 w1 = {c89, cab, ccd, cef};
    f16x8 pa0 = __builtin_bit_cast(f16x8, w0);
    f16x8 pa1 = __builtin_bit_cast(f16x8, w1);

    __builtin_amdgcn_s_setprio(1);
#pragma unroll
    for (int dh = 0; dh < 2; ++dh) {
      const u32 row = (u32)(dh * 32 + l31);
#pragma unroll
      for (int s2 = 0; s2 < 2; ++s2) {
        f16x8 vf = *(const f16x8*)(sVb + row * 64 +
                                   (((4 * jh + 2 * s2 + hi) ^ (row & 7)) * 8));
        oacc[dh] = __builtin_amdgcn_mfma_f32_32x32x16_f16(
            vf, (s2 == 0) ? pa0 : pa1, oacc[dh], 0, 0, 0);
      }
    }
    __builtin_amdgcn_s_setprio(0);
    __syncthreads();
  }

  ls += __shfl_xor(ls, 32);

  float* obuf = (float*)sK;  // [64 q][64 d] f32 = 16 KB, chunk-swizzled by q&15
  float* lbuf = (float*)sV;  // 64 f32
  const int q = qh * 32 + l31;
  if (jh == 1) {
#pragma unroll
    for (int dh = 0; dh < 2; ++dh)
#pragma unroll
      for (int g = 0; g < 4; ++g) {
        int ch = dh * 8 + g * 2 + hi;
        f32x4 wv = {oacc[dh][4 * g + 0], oacc[dh][4 * g + 1],
                    oacc[dh][4 * g + 2], oacc[dh][4 * g + 3]};
        *(f32x4*)(obuf + q * 64 + ((ch ^ (q & 15)) * 4)) = wv;
      }
    if (hi == 0) lbuf[q] = ls;
  }
  __syncthreads();
  if (jh == 0) {
    float inv = 1.0f / (ls + lbuf[q]);
    u16* orow = obase + (size_t)qcol * 1024;
#pragma unroll
    for (int dh = 0; dh < 2; ++dh)
#pragma unroll
      for (int g = 0; g < 4; ++g) {
        int ch = dh * 8 + g * 2 + hi;
        f32x4 po = *(const f32x4*)(obuf + q * 64 + ((ch ^ (q & 15)) * 4));
        float o0 = (oacc[dh][4 * g + 0] + po[0]) * inv;
        float o1 = (oacc[dh][4 * g + 1] + po[1]) * inv;
        float o2 = (oacc[dh][4 * g + 2] + po[2]) * inv;
        float o3 = (oacc[dh][4 * g + 3] + po[3]) * inv;
        *(uint2*)(orow + dh * 32 + g * 8 + hi * 4) = make_uint2(pack2(o0, o1), pack2(o2, o3));
      }
  }
}

// ---------------- launch ----------------
extern "C" void kernel_launch(void* const* d_in, const int* in_sizes, int n_in,
                              void* d_out, int out_size, void* d_ws, size_t ws_size,
                              hipStream_t stream) {
  const float* x = (const float*)d_in[0];      // [2,2048,1024]
  const float* w_qkv = (const float*)d_in[1];  // [1024,3072]
  const float* w_out = (const float*)d_in[2];  // [1024,1024]
  float* out = (float*)d_out;                  // [2,2048,1024] fp32

  char* ws = (char*)d_ws;
  u16* xb    = (u16*)(ws);                //  8 MB: x bf16 [4096,1024]
  u16* wqkvT = (u16*)(ws + (8u << 20));   //  6 MB: w_qkv^T bf16 [3072,1024]
  u16* woutT = (u16*)(ws + (14u << 20));  //  2 MB: w_out^T bf16 [1024,1024]
  u16* qkb   = (u16*)(ws + (16u << 20));  // 16 MB: q|k bf16 [4096,2048]
  u16* vtb   = (u16*)(ws + (32u << 20));  //  8 MB: V^T f16 [32,64,2048]
  u16* attn  = (u16*)(ws + (40u << 20));  //  8 MB: attn out bf16 [4096,1024]

  prepass_kernel<<<5120, 256, 0, stream>>>(x, w_qkv, w_out, xb, wqkvT, woutT);

  gemm_qkv128_kernel<<<512, 512, 0, stream>>>(xb, wqkvT, qkb, vtb);

  attn_mfma_kernel<<<1024, 256, 0, stream>>>(qkb, vtb, attn);

  gemm_out_kernel<<<512, 256, 0, stream>>>(attn, woutT, out);
}

// Round 16
// 161.626 us; speedup vs baseline: 1.0021x; 1.0021x over previous
//
#include <hip/hip_runtime.h>

typedef unsigned short u16;
typedef unsigned int u32;

typedef __bf16 bf16x8 __attribute__((ext_vector_type(8)));
typedef _Float16 f16x8 __attribute__((ext_vector_type(8)));
typedef float f32x4 __attribute__((ext_vector_type(4)));
typedef float f32x16 __attribute__((ext_vector_type(16)));
typedef u32 u32x4 __attribute__((ext_vector_type(4)));

typedef __attribute__((address_space(1))) u32 as1_u32;
typedef __attribute__((address_space(3))) u32 as3_u32;

#define EKF 0.18033688011112042f  // 0.125 * log2(e), folded into Q at GEMM1

__device__ __forceinline__ u16 f2bf(float x) {
  u32 u = __float_as_uint(x);
  u = u + 0x7fffu + ((u >> 16) & 1u);   // RNE
  return (u16)(u >> 16);
}
__device__ __forceinline__ u32 pack2(float a, float b) {
  return (u32)f2bf(a) | ((u32)f2bf(b) << 16);
}
__device__ __forceinline__ u32 pkf16(float a, float b) {
  return __builtin_bit_cast(u32, __builtin_amdgcn_cvt_pkrtz(a, b));
}
__device__ __forceinline__ u16 f2h(float a) {
  return (u16)(pkf16(a, a) & 0xffffu);
}
__device__ __forceinline__ void gld_lds16(const u16* g, const u16* l) {
  __builtin_amdgcn_global_load_lds((const as1_u32*)g, (as3_u32*)l, 16, 0, 0);
}

// ---------------- fused prepass: x cast + both weight transposes ----------------
__global__ __launch_bounds__(256) void prepass_kernel(const float* __restrict__ x,
                                                      const float* __restrict__ w_qkv,
                                                      const float* __restrict__ w_out,
                                                      u16* __restrict__ xb,
                                                      u16* __restrict__ wqkvT,
                                                      u16* __restrict__ woutT) {
  __shared__ float tile[64][65];
  int bid = blockIdx.x;
  int t = threadIdx.x;
  if (bid < 4096) {
    int i = bid * 256 + t;
    float4 v = ((const float4*)x)[i];
    uint2 r;
    r.x = pack2(v.x, v.y);
    r.y = pack2(v.z, v.w);
    ((uint2*)xb)[i] = r;
    return;
  }
  const float* W;
  u16* WT;
  int K, N, bx, by;
  if (bid < 4096 + 768) {
    int b2 = bid - 4096;
    W = w_qkv; WT = wqkvT; K = 1024; N = 3072; bx = b2 & 15; by = b2 >> 4;
  } else {
    int b2 = bid - 4864;
    W = w_out; WT = woutT; K = 1024; N = 1024; bx = b2 & 15; by = b2 >> 4;
  }
  int k0 = bx * 64, n0 = by * 64;
  int r = t >> 4, c4 = (t & 15) * 4;
#pragma unroll
  for (int i = 0; i < 4; ++i) {
    int row = r + i * 16;
    float4 v = *(const float4*)&W[(size_t)(k0 + row) * N + n0 + c4];
    tile[row][c4 + 0] = v.x; tile[row][c4 + 1] = v.y;
    tile[row][c4 + 2] = v.z; tile[row][c4 + 3] = v.w;
  }
  __syncthreads();
#pragma unroll
  for (int i = 0; i < 4; ++i) {
    int n = r + i * 16;
    uint2 o;
    o.x = pack2(tile[c4 + 0][n], tile[c4 + 1][n]);
    o.y = pack2(tile[c4 + 2][n], tile[c4 + 3][n]);
    *(uint2*)&WT[(size_t)(n0 + n) * K + k0 + c4] = o;
  }
}

// ---------------- QKV GEMM v3 (unchanged from R11): 128x192, 512 blocks ----------
__global__ __launch_bounds__(512, 4) void gemm_qkv128_kernel(const u16* __restrict__ A,
                                                             const u16* __restrict__ BT,
                                                             u16* __restrict__ QK,
                                                             u16* __restrict__ VT) {
  __shared__ __attribute__((aligned(16))) u16 smem[40960];  // 80 KiB: 2 x (8192 + 12288)
  const int tid = threadIdx.x;
  const int wave = tid >> 6;
  const int lane = tid & 63;
  const int lr = lane & 15;
  const int kg = lane >> 4;
  const int l7 = lr & 7;
  const int wr = wave >> 2;   // 0..1 : M half (64 rows)
  const int wc = wave & 3;    // 0..3 : N quarter (48 cols)

  const int b = blockIdx.x;
  const int xcd = b & 7, loc = b >> 3;            // loc 0..63
  const int bm = (xcd * 4 + (loc >> 4)) * 128;    // 32 M-tiles, 4 per XCD
  const int bn = (loc & 15) * 192;                // 16 N-tiles

  const int srow = tid >> 3;                      // 0..63
  const int scg = ((tid & 7) ^ (srow & 7)) * 8;   // swizzled source col (u16)
  const u16* pa = A + (size_t)(bm + srow) * 1024 + scg;
  const u16* pb = BT + (size_t)(bn + srow) * 1024 + scg;
  const u32 lw = (u32)wave * 512;

  f32x4 acc[4][3];
#pragma unroll
  for (int i = 0; i < 4; ++i)
#pragma unroll
    for (int j = 0; j < 3; ++j) {
      f32x4 z = {0.f, 0.f, 0.f, 0.f};
      acc[i][j] = z;
    }

  {  // prologue: stage tile 0 into buffer 0
    u16* dA = (u16*)smem;
    u16* dB = (u16*)smem + 8192;
#pragma unroll
    for (int i = 0; i < 2; ++i) gld_lds16(pa + (size_t)(i * 64) * 1024, dA + lw + i * 4096);
#pragma unroll
    for (int i = 0; i < 3; ++i) gld_lds16(pb + (size_t)(i * 64) * 1024, dB + lw + i * 4096);
  }

  for (int t = 0; t < 16; ++t) {
    __syncthreads();
    const u16* bA = smem + (t & 1) * 20480;
    const u16* bB = bA + 8192;
    if (t + 1 < 16) {
      u16* dA = (u16*)smem + ((t + 1) & 1) * 20480;
      u16* dB = dA + 8192;
      const int k1 = (t + 1) * 64;
#pragma unroll
      for (int i = 0; i < 2; ++i) gld_lds16(pa + (size_t)(i * 64) * 1024 + k1, dA + lw + i * 4096);
#pragma unroll
      for (int i = 0; i < 3; ++i) gld_lds16(pb + (size_t)(i * 64) * 1024 + k1, dB + lw + i * 4096);
    }
#pragma unroll
    for (int kk = 0; kk < 2; ++kk) {
      const int ch = ((kk * 4 + kg) ^ l7) * 8;
      bf16x8 af[4], bfr[3];
#pragma unroll
      for (int mi = 0; mi < 4; ++mi)
        af[mi] = *(const bf16x8*)(bA + (wr * 64 + mi * 16 + lr) * 64 + ch);
#pragma unroll
      for (int ni = 0; ni < 3; ++ni)
        bfr[ni] = *(const bf16x8*)(bB + (wc * 48 + ni * 16 + lr) * 64 + ch);
      __builtin_amdgcn_s_setprio(1);
#pragma unroll
      for (int mi = 0; mi < 4; ++mi)
#pragma unroll
        for (int ni = 0; ni < 3; ++ni)
          acc[mi][ni] = __builtin_amdgcn_mfma_f32_16x16x32_bf16(bfr[ni], af[mi], acc[mi][ni], 0, 0, 0);
      __builtin_amdgcn_s_setprio(0);
    }
  }

  __syncthreads();
#pragma unroll
  for (int i = 0; i < 4; ++i)
#pragma unroll
    for (int ni = 0; ni < 3; ++ni) {
      const int coff = wc * 48 + ni * 16 + kg * 4;  // col-in-tile
      const int cglob = bn + coff;
      f32x4 a = acc[i][ni];
      if (cglob >= 2048) {
        int r = bm + wr * 64 + i * 16 + lr;
        int cc = cglob - 2048;
        int bh2 = (r >> 11) * 16 + (cc >> 6);
        int j = r & 2047;
        u16* vrow = VT + ((size_t)bh2 * 64 + (cc & 63)) * 2048 + j;
#pragma unroll
        for (int rr = 0; rr < 4; ++rr) vrow[(size_t)rr * 2048] = f2h(a[rr]);
      } else {
        float scale = (cglob < 1024) ? EKF : 1.0f;
        int row = wr * 64 + i * 16 + lr;    // 0..127
        int chunk = coff >> 2;              // 0..47
        u32 off = (u32)row * 192 + (u32)((chunk ^ (row & 6)) << 2);
        *(uint2*)((u16*)smem + off) =
            make_uint2(pack2(a[0] * scale, a[1] * scale), pack2(a[2] * scale, a[3] * scale));
      }
    }
  __syncthreads();
  if (bn < 2048) {
#pragma unroll
    for (int i2 = 0; i2 < 8; ++i2) {
      int row = i2 * 16 + (tid >> 5);
      int lc = tid & 31;
      if (lc < 24 && bn + lc * 8 < 2048) {
        uint4 v = *(const uint4*)((const u16*)smem + (u32)row * 192 +
                                  (u32)(((2 * lc) ^ (row & 6)) * 4));
        *(uint4*)(QK + (size_t)(bm + row) * 2048 + bn + lc * 8) = v;
      }
    }
  }
}

// ---------------- out-proj GEMM (unchanged from R5) ----------------
__global__ __launch_bounds__(256, 2) void gemm_out_kernel(const u16* __restrict__ A,
                                                          const u16* __restrict__ BT,
                                                          float* __restrict__ C) {
  __shared__ __attribute__((aligned(16))) u16 smem[2][12288];  // A 64x64 + B 128x64 per buf
  const int tid = threadIdx.x;
  const int wave = tid >> 6;
  const int lane = tid & 63;
  const int lr = lane & 15;
  const int kg = lane >> 4;
  const int lr7 = lr & 7;
  const int wm = (wave >> 1) * 32;  // M half (32 rows per wave)
  const int wn = (wave & 1) * 64;   // N half (64 cols per wave)

  const int b = blockIdx.x;
  const int xcd = b & 7, loc = b >> 3;           // loc 0..63
  const int bm = (xcd * 8 + (loc >> 3)) * 64;    // 64 M-panels, 8 per XCD
  const int bn = (loc & 7) * 128;                // 8 N-tiles

  const int sr = tid >> 3;                        // 0..31
  const int scg = ((tid & 7) ^ (sr & 7)) * 8;     // swizzled source col (u16)
  const u16* pa = A + (size_t)(bm + sr) * 1024 + scg;
  const u16* pb = BT + (size_t)(bn + sr) * 1024 + scg;
  const u32 lw = (u32)wave * 512;

  f32x4 acc[2][4];
#pragma unroll
  for (int i = 0; i < 2; ++i)
#pragma unroll
    for (int j = 0; j < 4; ++j) {
      f32x4 z = {0.f, 0.f, 0.f, 0.f};
      acc[i][j] = z;
    }

  {  // prologue: stage tile 0 into buffer 0
    u16* dA = smem[0];
    u16* dB = smem[0] + 4096;
#pragma unroll
    for (int i = 0; i < 2; ++i) gld_lds16(pa + (size_t)(i * 32) * 1024, dA + lw + i * 2048);
#pragma unroll
    for (int i = 0; i < 4; ++i) gld_lds16(pb + (size_t)(i * 32) * 1024, dB + lw + i * 2048);
  }

  for (int t = 0; t < 16; ++t) {
    __syncthreads();  // tile t's loads complete
    const u16* bA = smem[t & 1];
    const u16* bB = bA + 4096;
    if (t + 1 < 16) {  // issue next tile with a full compute-phase of lead
      u16* dA = smem[(t + 1) & 1];
      u16* dB = dA + 4096;
      const int k1 = (t + 1) * 64;
#pragma unroll
      for (int i = 0; i < 2; ++i) gld_lds16(pa + (size_t)(i * 32) * 1024 + k1, dA + lw + i * 2048);
#pragma unroll
      for (int i = 0; i < 4; ++i) gld_lds16(pb + (size_t)(i * 32) * 1024 + k1, dB + lw + i * 2048);
    }
#pragma unroll
    for (int kk = 0; kk < 2; ++kk) {
      const int ch = ((kk * 4 + kg) ^ lr7) * 8;
      bf16x8 af[2], bfr[4];
#pragma unroll
      for (int mi = 0; mi < 2; ++mi)
        af[mi] = *(const bf16x8*)(bA + (wm + mi * 16 + lr) * 64 + ch);
#pragma unroll
      for (int ni = 0; ni < 4; ++ni)
        bfr[ni] = *(const bf16x8*)(bB + (wn + ni * 16 + lr) * 64 + ch);
      __builtin_amdgcn_s_setprio(1);
#pragma unroll
      for (int mi = 0; mi < 2; ++mi)
#pragma unroll
        for (int ni = 0; ni < 4; ++ni)
          acc[mi][ni] = __builtin_amdgcn_mfma_f32_16x16x32_bf16(bfr[ni], af[mi], acc[mi][ni], 0, 0, 0);
      __builtin_amdgcn_s_setprio(0);
    }
  }

  // epilogue: stage fp32 [64][64] col-halves through LDS, coalesced float4 out
  float* buf = (float*)smem;
#pragma unroll
  for (int hc = 0; hc < 2; ++hc) {
    __syncthreads();
    if ((wave & 1) == hc) {
#pragma unroll
      for (int mi = 0; mi < 2; ++mi)
#pragma unroll
        for (int ni = 0; ni < 4; ++ni) {
          int row = wm + mi * 16 + lr;                 // 0..63 (two waves cover all)
          int cp = ((ni * 4 + kg) ^ lr) * 4;           // 16-chunk swizzle, key lr
          *(f32x4*)(buf + row * 64 + cp) = acc[mi][ni];
        }
    }
    __syncthreads();
#pragma unroll
    for (int i = 0; i < 4; ++i) {
      int row = i * 16 + (tid >> 4);
      int lc = tid & 15;
      float4 v = *(const float4*)(buf + row * 64 + ((lc ^ (row & 15)) * 4));
      *(float4*)(C + (size_t)(bm + row) * 1024 + bn + hc * 64 + lc * 4) = v;
    }
  }
}

// ---------------- MFMA flash attention v15b: R13's verified v15 + QK setprio ------
// Reverted from the ones-MFMA lsum (v16/v16b): f16-RTZ-quantized denominator costs
// ~4 bf16 ulps (absmax 0.033 > 0.0292). VALU lsum tree restored (proven 0.0078).
// Balanced (qi,bh) map + wave-uniform diag branch retained (R13-verified).
// NEW (low-risk): s_setprio(1) also wraps the QK MFMA cluster (m191: setprio
// positive on attn; v15 only wrapped PV).
__global__ __launch_bounds__(256, 4) void attn_mfma_kernel(const u16* __restrict__ qk,
                                                           const u16* __restrict__ vt,
                                                           u16* __restrict__ out) {
  __shared__ __attribute__((aligned(16))) u16 sK[2][64 * 64];  // [j][d] swizzled
  __shared__ __attribute__((aligned(16))) u16 sV[2][64 * 64];  // [d][j] swizzled

  const int tid = threadIdx.x;
  const int wave = tid >> 6;
  const int lane = tid & 63;
  const int l31 = lane & 31;
  const int hi = lane >> 5;
  const int qh = wave & 1;   // q half (32 rows of the 64-q tile)
  const int jh = wave >> 1;  // j half (32 cols of each 64-j tile)

  const int idx = blockIdx.x;
  const int kq = idx >> 8;       // 0..3
  const int ci = idx & 255;
  const int w = ci >> 5;         // 0..7
  const int qi = (kq == 0) ? (31 - w) : (kq == 1) ? w : (kq == 2) ? (16 + w) : (15 - w);
  const int bh = (ci & 7) * 4 + ((ci >> 3) & 3);  // XCD-local bh grouping
  const int b = bh >> 4, h = bh & 15;
  const int q0 = qi * 64;

  const u16* qbase = qk + (size_t)b * 2048 * 2048 + h * 64;
  const u16* kbase = qbase + 1024;
  const u16* vbase = vt + (size_t)bh * 64 * 2048;
  u16* obase = out + (size_t)b * 2048 * 1024 + h * 64;

  const int sra = wave * 16 + (lane >> 3);
  const int srb = sra + 8;
  const int sc = lane & 7;
  const u32 koffA = (u32)sra * 2048 + (u32)((sc ^ (sra & 7)) * 8);
  const u32 koffB = (u32)srb * 2048 + (u32)((sc ^ (srb & 7)) * 8);
  const u32 ldsA = (wave * 2 + 0) * 512;
  const u32 ldsB = (wave * 2 + 1) * 512;

  const int qcol = q0 + qh * 32 + l31;
  bf16x8 qf[4];
  {
    const u16* qrow = qbase + (size_t)qcol * 2048;
#pragma unroll
    for (int s = 0; s < 4; ++s) qf[s] = *(const bf16x8*)(qrow + s * 16 + hi * 8);
  }

  f32x16 oacc[2];
#pragma unroll
  for (int i = 0; i < 16; ++i) { oacc[0][i] = 0.f; oacc[1][i] = 0.f; }
  float ls = 0.f;

  const int nrounds = qi + 1;
  gld_lds16(kbase + koffA, sK[0] + ldsA);
  gld_lds16(kbase + koffB, sK[0] + ldsB);
  gld_lds16(vbase + koffA, sV[0] + ldsA);
  gld_lds16(vbase + koffB, sV[0] + ldsB);
  __syncthreads();

  for (int t = 0; t < nrounds; ++t) {
    if (t + 1 < nrounds) {
      int j1 = (t + 1) * 64;
      u16* dK = sK[(t + 1) & 1];
      u16* dV = sV[(t + 1) & 1];
      gld_lds16(kbase + (size_t)j1 * 2048 + koffA, dK + ldsA);
      gld_lds16(kbase + (size_t)j1 * 2048 + koffB, dK + ldsB);
      gld_lds16(vbase + j1 + koffA, dV + ldsA);
      gld_lds16(vbase + j1 + koffB, dV + ldsB);
    }
    const u16* sKb = sK[t & 1];
    const u16* sVb = sV[t & 1];
    const bool diag = (t == qi);

    f32x16 c;
#pragma unroll
    for (int i = 0; i < 16; ++i) c[i] = 0.f;
    __builtin_amdgcn_s_setprio(1);
#pragma unroll
    for (int s = 0; s < 4; ++s) {
      const u32 row = (u32)(jh * 32 + l31);
      bf16x8 kf = *(const bf16x8*)(sKb + row * 64 + (((2 * s + hi) ^ (row & 7)) * 8));
      c = __builtin_amdgcn_mfma_f32_32x32x16_bf16(kf, qf[s], c, 0, 0, 0);
    }
    __builtin_amdgcn_s_setprio(0);
    float p[16];
    if (diag) {  // wave-uniform branch: mask VALU only on the diagonal round
      const int qrel = qh * 32 + l31;
#pragma unroll
      for (int r = 0; r < 16; ++r) {
        int joff = jh * 32 + (r & 3) + 8 * (r >> 2) + 4 * hi;
        float e = exp2f(c[r]);
        p[r] = (joff <= qrel) ? e : 0.f;
      }
    } else {
#pragma unroll
      for (int r = 0; r < 16; ++r) p[r] = exp2f(c[r]);
    }
    {
      float s0 = (p[0] + p[1]) + (p[2] + p[3]);
      float s1 = (p[4] + p[5]) + (p[6] + p[7]);
      float s2 = (p[8] + p[9]) + (p[10] + p[11]);
      float s3 = (p[12] + p[13]) + (p[14] + p[15]);
      ls += (s0 + s1) + (s2 + s3);
    }
    u32 c01 = pkf16(p[0], p[1]),   c23 = pkf16(p[2], p[3]);
    u32 c45 = pkf16(p[4], p[5]),   c67 = pkf16(p[6], p[7]);
    u32 c89 = pkf16(p[8], p[9]),   cab = pkf16(p[10], p[11]);
    u32 ccd = pkf16(p[12], p[13]), cef = pkf16(p[14], p[15]);
    asm volatile("v_permlane32_swap_b32 %0, %1" : "+v"(c01), "+v"(c45));
    asm volatile("v_permlane32_swap_b32 %0, %1" : "+v"(c23), "+v"(c67));
    asm volatile("v_permlane32_swap_b32 %0, %1" : "+v"(c89), "+v"(ccd));
    asm volatile("v_permlane32_swap_b32 %0, %1" : "+v"(cab), "+v"(cef));
    u32x4 w0 = {c01, c23, c45, c67};
    u32x4 w1 = {c89, cab, ccd, cef};
    f16x8 pa0 = __builtin_bit_cast(f16x8, w0);
    f16x8 pa1 = __builtin_bit_cast(f16x8, w1);

    __builtin_amdgcn_s_setprio(1);
#pragma unroll
    for (int dh = 0; dh < 2; ++dh) {
      const u32 row = (u32)(dh * 32 + l31);
#pragma unroll
      for (int s2 = 0; s2 < 2; ++s2) {
        f16x8 vf = *(const f16x8*)(sVb + row * 64 +
                                   (((4 * jh + 2 * s2 + hi) ^ (row & 7)) * 8));
        oacc[dh] = __builtin_amdgcn_mfma_f32_32x32x16_f16(
            vf, (s2 == 0) ? pa0 : pa1, oacc[dh], 0, 0, 0);
      }
    }
    __builtin_amdgcn_s_setprio(0);
    __syncthreads();
  }

  ls += __shfl_xor(ls, 32);

  float* obuf = (float*)sK;  // [64 q][64 d] f32 = 16 KB, chunk-swizzled by q&15
  float* lbuf = (float*)sV;  // 64 f32
  const int q = qh * 32 + l31;
  if (jh == 1) {
#pragma unroll
    for (int dh = 0; dh < 2; ++dh)
#pragma unroll
      for (int g = 0; g < 4; ++g) {
        int ch = dh * 8 + g * 2 + hi;
        f32x4 wv = {oacc[dh][4 * g + 0], oacc[dh][4 * g + 1],
                    oacc[dh][4 * g + 2], oacc[dh][4 * g + 3]};
        *(f32x4*)(obuf + q * 64 + ((ch ^ (q & 15)) * 4)) = wv;
      }
    if (hi == 0) lbuf[q] = ls;
  }
  __syncthreads();
  if (jh == 0) {
    float inv = 1.0f / (ls + lbuf[q]);
    u16* orow = obase + (size_t)qcol * 1024;
#pragma unroll
    for (int dh = 0; dh < 2; ++dh)
#pragma unroll
      for (int g = 0; g < 4; ++g) {
        int ch = dh * 8 + g * 2 + hi;
        f32x4 po = *(const f32x4*)(obuf + q * 64 + ((ch ^ (q & 15)) * 4));
        float o0 = (oacc[dh][4 * g + 0] + po[0]) * inv;
        float o1 = (oacc[dh][4 * g + 1] + po[1]) * inv;
        float o2 = (oacc[dh][4 * g + 2] + po[2]) * inv;
        float o3 = (oacc[dh][4 * g + 3] + po[3]) * inv;
        *(uint2*)(orow + dh * 32 + g * 8 + hi * 4) = make_uint2(pack2(o0, o1), pack2(o2, o3));
      }
  }
}

// ---------------- launch ----------------
extern "C" void kernel_launch(void* const* d_in, const int* in_sizes, int n_in,
                              void* d_out, int out_size, void* d_ws, size_t ws_size,
                              hipStream_t stream) {
  const float* x = (const float*)d_in[0];      // [2,2048,1024]
  const float* w_qkv = (const float*)d_in[1];  // [1024,3072]
  const float* w_out = (const float*)d_in[2];  // [1024,1024]
  float* out = (float*)d_out;                  // [2,2048,1024] fp32

  char* ws = (char*)d_ws;
  u16* xb    = (u16*)(ws);                //  8 MB: x bf16 [4096,1024]
  u16* wqkvT = (u16*)(ws + (8u << 20));   //  6 MB: w_qkv^T bf16 [3072,1024]
  u16* woutT = (u16*)(ws + (14u << 20));  //  2 MB: w_out^T bf16 [1024,1024]
  u16* qkb   = (u16*)(ws + (16u << 20));  // 16 MB: q|k bf16 [4096,2048]
  u16* vtb   = (u16*)(ws + (32u << 20));  //  8 MB: V^T f16 [32,64,2048]
  u16* attn  = (u16*)(ws + (40u << 20));  //  8 MB: attn out bf16 [4096,1024]

  prepass_kernel<<<5120, 256, 0, stream>>>(x, w_qkv, w_out, xb, wqkvT, woutT);

  gemm_qkv128_kernel<<<512, 512, 0, stream>>>(xb, wqkvT, qkb, vtb);

  attn_mfma_kernel<<<1024, 256, 0, stream>>>(qkb, vtb, attn);

  gemm_out_kernel<<<512, 256, 0, stream>>>(attn, woutT, out);
}

// Round 17
// 159.938 us; speedup vs baseline: 1.0127x; 1.0105x over previous
//
#include <hip/hip_runtime.h>

typedef unsigned short u16;
typedef unsigned int u32;

typedef __bf16 bf16x8 __attribute__((ext_vector_type(8)));
typedef _Float16 f16x8 __attribute__((ext_vector_type(8)));
typedef float f32x4 __attribute__((ext_vector_type(4)));
typedef float f32x16 __attribute__((ext_vector_type(16)));
typedef u32 u32x4 __attribute__((ext_vector_type(4)));

typedef __attribute__((address_space(1))) u32 as1_u32;
typedef __attribute__((address_space(3))) u32 as3_u32;

#define EKF 0.18033688011112042f  // 0.125 * log2(e), folded into Q at GEMM1

__device__ __forceinline__ u16 f2bf(float x) {
  u32 u = __float_as_uint(x);
  u = u + 0x7fffu + ((u >> 16) & 1u);   // RNE
  return (u16)(u >> 16);
}
__device__ __forceinline__ u32 pack2(float a, float b) {
  return (u32)f2bf(a) | ((u32)f2bf(b) << 16);
}
__device__ __forceinline__ u32 pkf16(float a, float b) {
  return __builtin_bit_cast(u32, __builtin_amdgcn_cvt_pkrtz(a, b));
}
__device__ __forceinline__ u16 f2h(float a) {
  return (u16)(pkf16(a, a) & 0xffffu);
}
__device__ __forceinline__ void gld_lds16(const u16* g, const u16* l) {
  __builtin_amdgcn_global_load_lds((const as1_u32*)g, (as3_u32*)l, 16, 0, 0);
}

// ---------------- fused prepass: x cast + both weight transposes ----------------
__global__ __launch_bounds__(256) void prepass_kernel(const float* __restrict__ x,
                                                      const float* __restrict__ w_qkv,
                                                      const float* __restrict__ w_out,
                                                      u16* __restrict__ xb,
                                                      u16* __restrict__ wqkvT,
                                                      u16* __restrict__ woutT) {
  __shared__ float tile[64][65];
  int bid = blockIdx.x;
  int t = threadIdx.x;
  if (bid < 4096) {
    int i = bid * 256 + t;
    float4 v = ((const float4*)x)[i];
    uint2 r;
    r.x = pack2(v.x, v.y);
    r.y = pack2(v.z, v.w);
    ((uint2*)xb)[i] = r;
    return;
  }
  const float* W;
  u16* WT;
  int K, N, bx, by;
  if (bid < 4096 + 768) {
    int b2 = bid - 4096;
    W = w_qkv; WT = wqkvT; K = 1024; N = 3072; bx = b2 & 15; by = b2 >> 4;
  } else {
    int b2 = bid - 4864;
    W = w_out; WT = woutT; K = 1024; N = 1024; bx = b2 & 15; by = b2 >> 4;
  }
  int k0 = bx * 64, n0 = by * 64;
  int r = t >> 4, c4 = (t & 15) * 4;
#pragma unroll
  for (int i = 0; i < 4; ++i) {
    int row = r + i * 16;
    float4 v = *(const float4*)&W[(size_t)(k0 + row) * N + n0 + c4];
    tile[row][c4 + 0] = v.x; tile[row][c4 + 1] = v.y;
    tile[row][c4 + 2] = v.z; tile[row][c4 + 3] = v.w;
  }
  __syncthreads();
#pragma unroll
  for (int i = 0; i < 4; ++i) {
    int n = r + i * 16;
    uint2 o;
    o.x = pack2(tile[c4 + 0][n], tile[c4 + 1][n]);
    o.y = pack2(tile[c4 + 2][n], tile[c4 + 3][n]);
    *(uint2*)&WT[(size_t)(n0 + n) * K + k0 + c4] = o;
  }
}

// ---------------- QKV GEMM v3 (unchanged from R11): 128x192, 512 blocks ----------
__global__ __launch_bounds__(512, 4) void gemm_qkv128_kernel(const u16* __restrict__ A,
                                                             const u16* __restrict__ BT,
                                                             u16* __restrict__ QK,
                                                             u16* __restrict__ VT) {
  __shared__ __attribute__((aligned(16))) u16 smem[40960];  // 80 KiB: 2 x (8192 + 12288)
  const int tid = threadIdx.x;
  const int wave = tid >> 6;
  const int lane = tid & 63;
  const int lr = lane & 15;
  const int kg = lane >> 4;
  const int l7 = lr & 7;
  const int wr = wave >> 2;   // 0..1 : M half (64 rows)
  const int wc = wave & 3;    // 0..3 : N quarter (48 cols)

  const int b = blockIdx.x;
  const int xcd = b & 7, loc = b >> 3;            // loc 0..63
  const int bm = (xcd * 4 + (loc >> 4)) * 128;    // 32 M-tiles, 4 per XCD
  const int bn = (loc & 15) * 192;                // 16 N-tiles

  const int srow = tid >> 3;                      // 0..63
  const int scg = ((tid & 7) ^ (srow & 7)) * 8;   // swizzled source col (u16)
  const u16* pa = A + (size_t)(bm + srow) * 1024 + scg;
  const u16* pb = BT + (size_t)(bn + srow) * 1024 + scg;
  const u32 lw = (u32)wave * 512;

  f32x4 acc[4][3];
#pragma unroll
  for (int i = 0; i < 4; ++i)
#pragma unroll
    for (int j = 0; j < 3; ++j) {
      f32x4 z = {0.f, 0.f, 0.f, 0.f};
      acc[i][j] = z;
    }

  {  // prologue: stage tile 0 into buffer 0
    u16* dA = (u16*)smem;
    u16* dB = (u16*)smem + 8192;
#pragma unroll
    for (int i = 0; i < 2; ++i) gld_lds16(pa + (size_t)(i * 64) * 1024, dA + lw + i * 4096);
#pragma unroll
    for (int i = 0; i < 3; ++i) gld_lds16(pb + (size_t)(i * 64) * 1024, dB + lw + i * 4096);
  }

  for (int t = 0; t < 16; ++t) {
    __syncthreads();
    const u16* bA = smem + (t & 1) * 20480;
    const u16* bB = bA + 8192;
    if (t + 1 < 16) {
      u16* dA = (u16*)smem + ((t + 1) & 1) * 20480;
      u16* dB = dA + 8192;
      const int k1 = (t + 1) * 64;
#pragma unroll
      for (int i = 0; i < 2; ++i) gld_lds16(pa + (size_t)(i * 64) * 1024 + k1, dA + lw + i * 4096);
#pragma unroll
      for (int i = 0; i < 3; ++i) gld_lds16(pb + (size_t)(i * 64) * 1024 + k1, dB + lw + i * 4096);
    }
#pragma unroll
    for (int kk = 0; kk < 2; ++kk) {
      const int ch = ((kk * 4 + kg) ^ l7) * 8;
      bf16x8 af[4], bfr[3];
#pragma unroll
      for (int mi = 0; mi < 4; ++mi)
        af[mi] = *(const bf16x8*)(bA + (wr * 64 + mi * 16 + lr) * 64 + ch);
#pragma unroll
      for (int ni = 0; ni < 3; ++ni)
        bfr[ni] = *(const bf16x8*)(bB + (wc * 48 + ni * 16 + lr) * 64 + ch);
      __builtin_amdgcn_s_setprio(1);
#pragma unroll
      for (int mi = 0; mi < 4; ++mi)
#pragma unroll
        for (int ni = 0; ni < 3; ++ni)
          acc[mi][ni] = __builtin_amdgcn_mfma_f32_16x16x32_bf16(bfr[ni], af[mi], acc[mi][ni], 0, 0, 0);
      __builtin_amdgcn_s_setprio(0);
    }
  }

  __syncthreads();
#pragma unroll
  for (int i = 0; i < 4; ++i)
#pragma unroll
    for (int ni = 0; ni < 3; ++ni) {
      const int coff = wc * 48 + ni * 16 + kg * 4;  // col-in-tile
      const int cglob = bn + coff;
      f32x4 a = acc[i][ni];
      if (cglob >= 2048) {
        int r = bm + wr * 64 + i * 16 + lr;
        int cc = cglob - 2048;
        int bh2 = (r >> 11) * 16 + (cc >> 6);
        int j = r & 2047;
        u16* vrow = VT + ((size_t)bh2 * 64 + (cc & 63)) * 2048 + j;
#pragma unroll
        for (int rr = 0; rr < 4; ++rr) vrow[(size_t)rr * 2048] = f2h(a[rr]);
      } else {
        float scale = (cglob < 1024) ? EKF : 1.0f;
        int row = wr * 64 + i * 16 + lr;    // 0..127
        int chunk = coff >> 2;              // 0..47
        u32 off = (u32)row * 192 + (u32)((chunk ^ (row & 6)) << 2);
        *(uint2*)((u16*)smem + off) =
            make_uint2(pack2(a[0] * scale, a[1] * scale), pack2(a[2] * scale, a[3] * scale));
      }
    }
  __syncthreads();
  if (bn < 2048) {
#pragma unroll
    for (int i2 = 0; i2 < 8; ++i2) {
      int row = i2 * 16 + (tid >> 5);
      int lc = tid & 31;
      if (lc < 24 && bn + lc * 8 < 2048) {
        uint4 v = *(const uint4*)((const u16*)smem + (u32)row * 192 +
                                  (u32)(((2 * lc) ^ (row & 6)) * 4));
        *(uint4*)(QK + (size_t)(bm + row) * 2048 + bn + lc * 8) = v;
      }
    }
  }
}

// ---------------- out-proj GEMM (unchanged from R5) ----------------
__global__ __launch_bounds__(256, 2) void gemm_out_kernel(const u16* __restrict__ A,
                                                          const u16* __restrict__ BT,
                                                          float* __restrict__ C) {
  __shared__ __attribute__((aligned(16))) u16 smem[2][12288];  // A 64x64 + B 128x64 per buf
  const int tid = threadIdx.x;
  const int wave = tid >> 6;
  const int lane = tid & 63;
  const int lr = lane & 15;
  const int kg = lane >> 4;
  const int lr7 = lr & 7;
  const int wm = (wave >> 1) * 32;  // M half (32 rows per wave)
  const int wn = (wave & 1) * 64;   // N half (64 cols per wave)

  const int b = blockIdx.x;
  const int xcd = b & 7, loc = b >> 3;           // loc 0..63
  const int bm = (xcd * 8 + (loc >> 3)) * 64;    // 64 M-panels, 8 per XCD
  const int bn = (loc & 7) * 128;                // 8 N-tiles

  const int sr = tid >> 3;                        // 0..31
  const int scg = ((tid & 7) ^ (sr & 7)) * 8;     // swizzled source col (u16)
  const u16* pa = A + (size_t)(bm + sr) * 1024 + scg;
  const u16* pb = BT + (size_t)(bn + sr) * 1024 + scg;
  const u32 lw = (u32)wave * 512;

  f32x4 acc[2][4];
#pragma unroll
  for (int i = 0; i < 2; ++i)
#pragma unroll
    for (int j = 0; j < 4; ++j) {
      f32x4 z = {0.f, 0.f, 0.f, 0.f};
      acc[i][j] = z;
    }

  {  // prologue: stage tile 0 into buffer 0
    u16* dA = smem[0];
    u16* dB = smem[0] + 4096;
#pragma unroll
    for (int i = 0; i < 2; ++i) gld_lds16(pa + (size_t)(i * 32) * 1024, dA + lw + i * 2048);
#pragma unroll
    for (int i = 0; i < 4; ++i) gld_lds16(pb + (size_t)(i * 32) * 1024, dB + lw + i * 2048);
  }

  for (int t = 0; t < 16; ++t) {
    __syncthreads();  // tile t's loads complete
    const u16* bA = smem[t & 1];
    const u16* bB = bA + 4096;
    if (t + 1 < 16) {  // issue next tile with a full compute-phase of lead
      u16* dA = smem[(t + 1) & 1];
      u16* dB = dA + 4096;
      const int k1 = (t + 1) * 64;
#pragma unroll
      for (int i = 0; i < 2; ++i) gld_lds16(pa + (size_t)(i * 32) * 1024 + k1, dA + lw + i * 2048);
#pragma unroll
      for (int i = 0; i < 4; ++i) gld_lds16(pb + (size_t)(i * 32) * 1024 + k1, dB + lw + i * 2048);
    }
#pragma unroll
    for (int kk = 0; kk < 2; ++kk) {
      const int ch = ((kk * 4 + kg) ^ lr7) * 8;
      bf16x8 af[2], bfr[4];
#pragma unroll
      for (int mi = 0; mi < 2; ++mi)
        af[mi] = *(const bf16x8*)(bA + (wm + mi * 16 + lr) * 64 + ch);
#pragma unroll
      for (int ni = 0; ni < 4; ++ni)
        bfr[ni] = *(const bf16x8*)(bB + (wn + ni * 16 + lr) * 64 + ch);
      __builtin_amdgcn_s_setprio(1);
#pragma unroll
      for (int mi = 0; mi < 2; ++mi)
#pragma unroll
        for (int ni = 0; ni < 4; ++ni)
          acc[mi][ni] = __builtin_amdgcn_mfma_f32_16x16x32_bf16(bfr[ni], af[mi], acc[mi][ni], 0, 0, 0);
      __builtin_amdgcn_s_setprio(0);
    }
  }

  // epilogue: stage fp32 [64][64] col-halves through LDS, coalesced float4 out
  float* buf = (float*)smem;
#pragma unroll
  for (int hc = 0; hc < 2; ++hc) {
    __syncthreads();
    if ((wave & 1) == hc) {
#pragma unroll
      for (int mi = 0; mi < 2; ++mi)
#pragma unroll
        for (int ni = 0; ni < 4; ++ni) {
          int row = wm + mi * 16 + lr;                 // 0..63 (two waves cover all)
          int cp = ((ni * 4 + kg) ^ lr) * 4;           // 16-chunk swizzle, key lr
          *(f32x4*)(buf + row * 64 + cp) = acc[mi][ni];
        }
    }
    __syncthreads();
#pragma unroll
    for (int i = 0; i < 4; ++i) {
      int row = i * 16 + (tid >> 4);
      int lc = tid & 15;
      float4 v = *(const float4*)(buf + row * 64 + ((lc ^ (row & 15)) * 4));
      *(float4*)(C + (size_t)(bm + row) * 1024 + bn + hc * 64 + lc * 4) = v;
    }
  }
}

// ---------------- MFMA flash attention v14 (exact R12 session-best config) --------
// Heavy-first qi + XCD bh-grouping; 32x32 quadrant waves with in-register P
// (permlane32 swaps); per-round masking; setprio around PV only; VALU lsum tree.
// R13/R16's balanced-map + diag-hoist + QK-setprio variants measured ~4 us worse
// e2e over two runs -> reverted to the verified 157.6-us configuration.
__global__ __launch_bounds__(256, 4) void attn_mfma_kernel(const u16* __restrict__ qk,
                                                           const u16* __restrict__ vt,
                                                           u16* __restrict__ out) {
  __shared__ __attribute__((aligned(16))) u16 sK[2][64 * 64];  // [j][d] swizzled
  __shared__ __attribute__((aligned(16))) u16 sV[2][64 * 64];  // [d][j] swizzled

  const int tid = threadIdx.x;
  const int wave = tid >> 6;
  const int lane = tid & 63;
  const int l31 = lane & 31;
  const int hi = lane >> 5;
  const int qh = wave & 1;   // q half (32 rows of the 64-q tile)
  const int jh = wave >> 1;  // j half (32 cols of each 64-j tile)

  int idx = blockIdx.x;
  int qi = 31 - (idx >> 5);                      // heavy q-tiles first
  int bh = (idx & 7) * 4 + ((idx >> 3) & 3);     // XCD-local bh grouping
  int b = bh >> 4, h = bh & 15;
  int q0 = qi * 64;

  const u16* qbase = qk + (size_t)b * 2048 * 2048 + h * 64;
  const u16* kbase = qbase + 1024;
  const u16* vbase = vt + (size_t)bh * 64 * 2048;
  u16* obase = out + (size_t)b * 2048 * 1024 + h * 64;

  const int sra = wave * 16 + (lane >> 3);
  const int srb = sra + 8;
  const int sc = lane & 7;
  const u32 koffA = (u32)sra * 2048 + (u32)((sc ^ (sra & 7)) * 8);
  const u32 koffB = (u32)srb * 2048 + (u32)((sc ^ (srb & 7)) * 8);
  const u32 ldsA = (wave * 2 + 0) * 512;
  const u32 ldsB = (wave * 2 + 1) * 512;

  const int qcol = q0 + qh * 32 + l31;
  bf16x8 qf[4];
  {
    const u16* qrow = qbase + (size_t)qcol * 2048;
#pragma unroll
    for (int s = 0; s < 4; ++s) qf[s] = *(const bf16x8*)(qrow + s * 16 + hi * 8);
  }

  f32x16 oacc[2];
#pragma unroll
  for (int i = 0; i < 16; ++i) { oacc[0][i] = 0.f; oacc[1][i] = 0.f; }
  float ls = 0.f;

  const int nrounds = qi + 1;
  gld_lds16(kbase + koffA, sK[0] + ldsA);
  gld_lds16(kbase + koffB, sK[0] + ldsB);
  gld_lds16(vbase + koffA, sV[0] + ldsA);
  gld_lds16(vbase + koffB, sV[0] + ldsB);
  __syncthreads();

  for (int t = 0; t < nrounds; ++t) {
    if (t + 1 < nrounds) {
      int j1 = (t + 1) * 64;
      u16* dK = sK[(t + 1) & 1];
      u16* dV = sV[(t + 1) & 1];
      gld_lds16(kbase + (size_t)j1 * 2048 + koffA, dK + ldsA);
      gld_lds16(kbase + (size_t)j1 * 2048 + koffB, dK + ldsB);
      gld_lds16(vbase + j1 + koffA, dV + ldsA);
      gld_lds16(vbase + j1 + koffB, dV + ldsB);
    }
    const u16* sKb = sK[t & 1];
    const u16* sVb = sV[t & 1];
    const bool diag = (t == qi);

    f32x16 c;
#pragma unroll
    for (int i = 0; i < 16; ++i) c[i] = 0.f;
#pragma unroll
    for (int s = 0; s < 4; ++s) {
      const u32 row = (u32)(jh * 32 + l31);
      bf16x8 kf = *(const bf16x8*)(sKb + row * 64 + (((2 * s + hi) ^ (row & 7)) * 8));
      c = __builtin_amdgcn_mfma_f32_32x32x16_bf16(kf, qf[s], c, 0, 0, 0);
    }
    float p[16];
    const int qrel = qh * 32 + l31;
#pragma unroll
    for (int r = 0; r < 16; ++r) {
      int joff = jh * 32 + (r & 3) + 8 * (r >> 2) + 4 * hi;
      float e = exp2f(c[r]);
      p[r] = (!diag || (joff <= qrel)) ? e : 0.f;
    }
    {
      float s0 = (p[0] + p[1]) + (p[2] + p[3]);
      float s1 = (p[4] + p[5]) + (p[6] + p[7]);
      float s2 = (p[8] + p[9]) + (p[10] + p[11]);
      float s3 = (p[12] + p[13]) + (p[14] + p[15]);
      ls += (s0 + s1) + (s2 + s3);
    }
    u32 c01 = pkf16(p[0], p[1]),   c23 = pkf16(p[2], p[3]);
    u32 c45 = pkf16(p[4], p[5]),   c67 = pkf16(p[6], p[7]);
    u32 c89 = pkf16(p[8], p[9]),   cab = pkf16(p[10], p[11]);
    u32 ccd = pkf16(p[12], p[13]), cef = pkf16(p[14], p[15]);
    asm volatile("v_permlane32_swap_b32 %0, %1" : "+v"(c01), "+v"(c45));
    asm volatile("v_permlane32_swap_b32 %0, %1" : "+v"(c23), "+v"(c67));
    asm volatile("v_permlane32_swap_b32 %0, %1" : "+v"(c89), "+v"(ccd));
    asm volatile("v_permlane32_swap_b32 %0, %1" : "+v"(cab), "+v"(cef));
    u32x4 w0 = {c01, c23, c45, c67};
    u32x4 w1 = {c89, cab, ccd, cef};
    f16x8 pa0 = __builtin_bit_cast(f16x8, w0);
    f16x8 pa1 = __builtin_bit_cast(f16x8, w1);

    __builtin_amdgcn_s_setprio(1);
#pragma unroll
    for (int dh = 0; dh < 2; ++dh) {
      const u32 row = (u32)(dh * 32 + l31);
#pragma unroll
      for (int s2 = 0; s2 < 2; ++s2) {
        f16x8 vf = *(const f16x8*)(sVb + row * 64 +
                                   (((4 * jh + 2 * s2 + hi) ^ (row & 7)) * 8));
        oacc[dh] = __builtin_amdgcn_mfma_f32_32x32x16_f16(
            vf, (s2 == 0) ? pa0 : pa1, oacc[dh], 0, 0, 0);
      }
    }
    __builtin_amdgcn_s_setprio(0);
    __syncthreads();
  }

  ls += __shfl_xor(ls, 32);

  float* obuf = (float*)sK;  // [64 q][64 d] f32 = 16 KB, chunk-swizzled by q&15
  float* lbuf = (float*)sV;  // 64 f32
  const int q = qh * 32 + l31;
  if (jh == 1) {
#pragma unroll
    for (int dh = 0; dh < 2; ++dh)
#pragma unroll
      for (int g = 0; g < 4; ++g) {
        int ch = dh * 8 + g * 2 + hi;
        f32x4 wv = {oacc[dh][4 * g + 0], oacc[dh][4 * g + 1],
                    oacc[dh][4 * g + 2], oacc[dh][4 * g + 3]};
        *(f32x4*)(obuf + q * 64 + ((ch ^ (q & 15)) * 4)) = wv;
      }
    if (hi == 0) lbuf[q] = ls;
  }
  __syncthreads();
  if (jh == 0) {
    float inv = 1.0f / (ls + lbuf[q]);
    u16* orow = obase + (size_t)qcol * 1024;
#pragma unroll
    for (int dh = 0; dh < 2; ++dh)
#pragma unroll
      for (int g = 0; g < 4; ++g) {
        int ch = dh * 8 + g * 2 + hi;
        f32x4 po = *(const f32x4*)(obuf + q * 64 + ((ch ^ (q & 15)) * 4));
        float o0 = (oacc[dh][4 * g + 0] + po[0]) * inv;
        float o1 = (oacc[dh][4 * g + 1] + po[1]) * inv;
        float o2 = (oacc[dh][4 * g + 2] + po[2]) * inv;
        float o3 = (oacc[dh][4 * g + 3] + po[3]) * inv;
        *(uint2*)(orow + dh * 32 + g * 8 + hi * 4) = make_uint2(pack2(o0, o1), pack2(o2, o3));
      }
  }
}

// ---------------- launch ----------------
extern "C" void kernel_launch(void* const* d_in, const int* in_sizes, int n_in,
                              void* d_out, int out_size, void* d_ws, size_t ws_size,
                              hipStream_t stream) {
  const float* x = (const float*)d_in[0];      // [2,2048,1024]
  const float* w_qkv = (const float*)d_in[1];  // [1024,3072]
  const float* w_out = (const float*)d_in[2];  // [1024,1024]
  float* out = (float*)d_out;                  // [2,2048,1024] fp32

  char* ws = (char*)d_ws;
  u16* xb    = (u16*)(ws);                //  8 MB: x bf16 [4096,1024]
  u16* wqkvT = (u16*)(ws + (8u << 20));   //  6 MB: w_qkv^T bf16 [3072,1024]
  u16* woutT = (u16*)(ws + (14u << 20));  //  2 MB: w_out^T bf16 [1024,1024]
  u16* qkb   = (u16*)(ws + (16u << 20));  // 16 MB: q|k bf16 [4096,2048]
  u16* vtb   = (u16*)(ws + (32u << 20));  //  8 MB: V^T f16 [32,64,2048]
  u16* attn  = (u16*)(ws + (40u << 20));  //  8 MB: attn out bf16 [4096,1024]

  prepass_kernel<<<5120, 256, 0, stream>>>(x, w_qkv, w_out, xb, wqkvT, woutT);

  gemm_qkv128_kernel<<<512, 512, 0, stream>>>(xb, wqkvT, qkb, vtb);

  attn_mfma_kernel<<<1024, 256, 0, stream>>>(qkb, vtb, attn);

  gemm_out_kernel<<<512, 256, 0, stream>>>(attn, woutT, out);
}

// Round 18
// 156.984 us; speedup vs baseline: 1.0318x; 1.0188x over previous
//
#include <hip/hip_runtime.h>

typedef unsigned short u16;
typedef unsigned int u32;

typedef __bf16 bf16x8 __attribute__((ext_vector_type(8)));
typedef _Float16 f16x8 __attribute__((ext_vector_type(8)));
typedef float f32x4 __attribute__((ext_vector_type(4)));
typedef float f32x16 __attribute__((ext_vector_type(16)));
typedef u32 u32x4 __attribute__((ext_vector_type(4)));

typedef __attribute__((address_space(1))) u32 as1_u32;
typedef __attribute__((address_space(3))) u32 as3_u32;

#define EKF 0.18033688011112042f  // 0.125 * log2(e), folded into Q at GEMM1

__device__ __forceinline__ u16 f2bf(float x) {
  u32 u = __float_as_uint(x);
  u = u + 0x7fffu + ((u >> 16) & 1u);   // RNE
  return (u16)(u >> 16);
}
__device__ __forceinline__ u32 pack2(float a, float b) {
  return (u32)f2bf(a) | ((u32)f2bf(b) << 16);
}
__device__ __forceinline__ u32 pkf16(float a, float b) {
  return __builtin_bit_cast(u32, __builtin_amdgcn_cvt_pkrtz(a, b));
}
__device__ __forceinline__ u16 f2h(float a) {
  return (u16)(pkf16(a, a) & 0xffffu);
}
__device__ __forceinline__ void gld_lds16(const u16* g, const u16* l) {
  __builtin_amdgcn_global_load_lds((const as1_u32*)g, (as3_u32*)l, 16, 0, 0);
}

// ---------------- fused prepass: x cast + both weight transposes ----------------
__global__ __launch_bounds__(256) void prepass_kernel(const float* __restrict__ x,
                                                      const float* __restrict__ w_qkv,
                                                      const float* __restrict__ w_out,
                                                      u16* __restrict__ xb,
                                                      u16* __restrict__ wqkvT,
                                                      u16* __restrict__ woutT) {
  __shared__ float tile[64][65];
  int bid = blockIdx.x;
  int t = threadIdx.x;
  if (bid < 4096) {
    int i = bid * 256 + t;
    float4 v = ((const float4*)x)[i];
    uint2 r;
    r.x = pack2(v.x, v.y);
    r.y = pack2(v.z, v.w);
    ((uint2*)xb)[i] = r;
    return;
  }
  const float* W;
  u16* WT;
  int K, N, bx, by;
  if (bid < 4096 + 768) {
    int b2 = bid - 4096;
    W = w_qkv; WT = wqkvT; K = 1024; N = 3072; bx = b2 & 15; by = b2 >> 4;
  } else {
    int b2 = bid - 4864;
    W = w_out; WT = woutT; K = 1024; N = 1024; bx = b2 & 15; by = b2 >> 4;
  }
  int k0 = bx * 64, n0 = by * 64;
  int r = t >> 4, c4 = (t & 15) * 4;
#pragma unroll
  for (int i = 0; i < 4; ++i) {
    int row = r + i * 16;
    float4 v = *(const float4*)&W[(size_t)(k0 + row) * N + n0 + c4];
    tile[row][c4 + 0] = v.x; tile[row][c4 + 1] = v.y;
    tile[row][c4 + 2] = v.z; tile[row][c4 + 3] = v.w;
  }
  __syncthreads();
#pragma unroll
  for (int i = 0; i < 4; ++i) {
    int n = r + i * 16;
    uint2 o;
    o.x = pack2(tile[c4 + 0][n], tile[c4 + 1][n]);
    o.y = pack2(tile[c4 + 2][n], tile[c4 + 3][n]);
    *(uint2*)&WT[(size_t)(n0 + n) * K + k0 + c4] = o;
  }
}

// ---------------- QKV GEMM v3 (unchanged from R11): 128x192, 512 blocks ----------
__global__ __launch_bounds__(512, 4) void gemm_qkv128_kernel(const u16* __restrict__ A,
                                                             const u16* __restrict__ BT,
                                                             u16* __restrict__ QK,
                                                             u16* __restrict__ VT) {
  __shared__ __attribute__((aligned(16))) u16 smem[40960];  // 80 KiB: 2 x (8192 + 12288)
  const int tid = threadIdx.x;
  const int wave = tid >> 6;
  const int lane = tid & 63;
  const int lr = lane & 15;
  const int kg = lane >> 4;
  const int l7 = lr & 7;
  const int wr = wave >> 2;   // 0..1 : M half (64 rows)
  const int wc = wave & 3;    // 0..3 : N quarter (48 cols)

  const int b = blockIdx.x;
  const int xcd = b & 7, loc = b >> 3;            // loc 0..63
  const int bm = (xcd * 4 + (loc >> 4)) * 128;    // 32 M-tiles, 4 per XCD
  const int bn = (loc & 15) * 192;                // 16 N-tiles

  const int srow = tid >> 3;                      // 0..63
  const int scg = ((tid & 7) ^ (srow & 7)) * 8;   // swizzled source col (u16)
  const u16* pa = A + (size_t)(bm + srow) * 1024 + scg;
  const u16* pb = BT + (size_t)(bn + srow) * 1024 + scg;
  const u32 lw = (u32)wave * 512;

  f32x4 acc[4][3];
#pragma unroll
  for (int i = 0; i < 4; ++i)
#pragma unroll
    for (int j = 0; j < 3; ++j) {
      f32x4 z = {0.f, 0.f, 0.f, 0.f};
      acc[i][j] = z;
    }

  {  // prologue: stage tile 0 into buffer 0
    u16* dA = (u16*)smem;
    u16* dB = (u16*)smem + 8192;
#pragma unroll
    for (int i = 0; i < 2; ++i) gld_lds16(pa + (size_t)(i * 64) * 1024, dA + lw + i * 4096);
#pragma unroll
    for (int i = 0; i < 3; ++i) gld_lds16(pb + (size_t)(i * 64) * 1024, dB + lw + i * 4096);
  }

  for (int t = 0; t < 16; ++t) {
    __syncthreads();
    const u16* bA = smem + (t & 1) * 20480;
    const u16* bB = bA + 8192;
    if (t + 1 < 16) {
      u16* dA = (u16*)smem + ((t + 1) & 1) * 20480;
      u16* dB = dA + 8192;
      const int k1 = (t + 1) * 64;
#pragma unroll
      for (int i = 0; i < 2; ++i) gld_lds16(pa + (size_t)(i * 64) * 1024 + k1, dA + lw + i * 4096);
#pragma unroll
      for (int i = 0; i < 3; ++i) gld_lds16(pb + (size_t)(i * 64) * 1024 + k1, dB + lw + i * 4096);
    }
#pragma unroll
    for (int kk = 0; kk < 2; ++kk) {
      const int ch = ((kk * 4 + kg) ^ l7) * 8;
      bf16x8 af[4], bfr[3];
#pragma unroll
      for (int mi = 0; mi < 4; ++mi)
        af[mi] = *(const bf16x8*)(bA + (wr * 64 + mi * 16 + lr) * 64 + ch);
#pragma unroll
      for (int ni = 0; ni < 3; ++ni)
        bfr[ni] = *(const bf16x8*)(bB + (wc * 48 + ni * 16 + lr) * 64 + ch);
      __builtin_amdgcn_s_setprio(1);
#pragma unroll
      for (int mi = 0; mi < 4; ++mi)
#pragma unroll
        for (int ni = 0; ni < 3; ++ni)
          acc[mi][ni] = __builtin_amdgcn_mfma_f32_16x16x32_bf16(bfr[ni], af[mi], acc[mi][ni], 0, 0, 0);
      __builtin_amdgcn_s_setprio(0);
    }
  }

  __syncthreads();
#pragma unroll
  for (int i = 0; i < 4; ++i)
#pragma unroll
    for (int ni = 0; ni < 3; ++ni) {
      const int coff = wc * 48 + ni * 16 + kg * 4;  // col-in-tile
      const int cglob = bn + coff;
      f32x4 a = acc[i][ni];
      if (cglob >= 2048) {
        int r = bm + wr * 64 + i * 16 + lr;
        int cc = cglob - 2048;
        int bh2 = (r >> 11) * 16 + (cc >> 6);
        int j = r & 2047;
        u16* vrow = VT + ((size_t)bh2 * 64 + (cc & 63)) * 2048 + j;
#pragma unroll
        for (int rr = 0; rr < 4; ++rr) vrow[(size_t)rr * 2048] = f2h(a[rr]);
      } else {
        float scale = (cglob < 1024) ? EKF : 1.0f;
        int row = wr * 64 + i * 16 + lr;    // 0..127
        int chunk = coff >> 2;              // 0..47
        u32 off = (u32)row * 192 + (u32)((chunk ^ (row & 6)) << 2);
        *(uint2*)((u16*)smem + off) =
            make_uint2(pack2(a[0] * scale, a[1] * scale), pack2(a[2] * scale, a[3] * scale));
      }
    }
  __syncthreads();
  if (bn < 2048) {
#pragma unroll
    for (int i2 = 0; i2 < 8; ++i2) {
      int row = i2 * 16 + (tid >> 5);
      int lc = tid & 31;
      if (lc < 24 && bn + lc * 8 < 2048) {
        uint4 v = *(const uint4*)((const u16*)smem + (u32)row * 192 +
                                  (u32)(((2 * lc) ^ (row & 6)) * 4));
        *(uint4*)(QK + (size_t)(bm + row) * 2048 + bn + lc * 8) = v;
      }
    }
  }
}

// ---------------- out-proj GEMM (unchanged from R5) ----------------
__global__ __launch_bounds__(256, 2) void gemm_out_kernel(const u16* __restrict__ A,
                                                          const u16* __restrict__ BT,
                                                          float* __restrict__ C) {
  __shared__ __attribute__((aligned(16))) u16 smem[2][12288];  // A 64x64 + B 128x64 per buf
  const int tid = threadIdx.x;
  const int wave = tid >> 6;
  const int lane = tid & 63;
  const int lr = lane & 15;
  const int kg = lane >> 4;
  const int lr7 = lr & 7;
  const int wm = (wave >> 1) * 32;  // M half (32 rows per wave)
  const int wn = (wave & 1) * 64;   // N half (64 cols per wave)

  const int b = blockIdx.x;
  const int xcd = b & 7, loc = b >> 3;           // loc 0..63
  const int bm = (xcd * 8 + (loc >> 3)) * 64;    // 64 M-panels, 8 per XCD
  const int bn = (loc & 7) * 128;                // 8 N-tiles

  const int sr = tid >> 3;                        // 0..31
  const int scg = ((tid & 7) ^ (sr & 7)) * 8;     // swizzled source col (u16)
  const u16* pa = A + (size_t)(bm + sr) * 1024 + scg;
  const u16* pb = BT + (size_t)(bn + sr) * 1024 + scg;
  const u32 lw = (u32)wave * 512;

  f32x4 acc[2][4];
#pragma unroll
  for (int i = 0; i < 2; ++i)
#pragma unroll
    for (int j = 0; j < 4; ++j) {
      f32x4 z = {0.f, 0.f, 0.f, 0.f};
      acc[i][j] = z;
    }

  {  // prologue: stage tile 0 into buffer 0
    u16* dA = smem[0];
    u16* dB = smem[0] + 4096;
#pragma unroll
    for (int i = 0; i < 2; ++i) gld_lds16(pa + (size_t)(i * 32) * 1024, dA + lw + i * 2048);
#pragma unroll
    for (int i = 0; i < 4; ++i) gld_lds16(pb + (size_t)(i * 32) * 1024, dB + lw + i * 2048);
  }

  for (int t = 0; t < 16; ++t) {
    __syncthreads();  // tile t's loads complete
    const u16* bA = smem[t & 1];
    const u16* bB = bA + 4096;
    if (t + 1 < 16) {  // issue next tile with a full compute-phase of lead
      u16* dA = smem[(t + 1) & 1];
      u16* dB = dA + 4096;
      const int k1 = (t + 1) * 64;
#pragma unroll
      for (int i = 0; i < 2; ++i) gld_lds16(pa + (size_t)(i * 32) * 1024 + k1, dA + lw + i * 2048);
#pragma unroll
      for (int i = 0; i < 4; ++i) gld_lds16(pb + (size_t)(i * 32) * 1024 + k1, dB + lw + i * 2048);
    }
#pragma unroll
    for (int kk = 0; kk < 2; ++kk) {
      const int ch = ((kk * 4 + kg) ^ lr7) * 8;
      bf16x8 af[2], bfr[4];
#pragma unroll
      for (int mi = 0; mi < 2; ++mi)
        af[mi] = *(const bf16x8*)(bA + (wm + mi * 16 + lr) * 64 + ch);
#pragma unroll
      for (int ni = 0; ni < 4; ++ni)
        bfr[ni] = *(const bf16x8*)(bB + (wn + ni * 16 + lr) * 64 + ch);
      __builtin_amdgcn_s_setprio(1);
#pragma unroll
      for (int mi = 0; mi < 2; ++mi)
#pragma unroll
        for (int ni = 0; ni < 4; ++ni)
          acc[mi][ni] = __builtin_amdgcn_mfma_f32_16x16x32_bf16(bfr[ni], af[mi], acc[mi][ni], 0, 0, 0);
      __builtin_amdgcn_s_setprio(0);
    }
  }

  // epilogue: stage fp32 [64][64] col-halves through LDS, coalesced float4 out
  float* buf = (float*)smem;
#pragma unroll
  for (int hc = 0; hc < 2; ++hc) {
    __syncthreads();
    if ((wave & 1) == hc) {
#pragma unroll
      for (int mi = 0; mi < 2; ++mi)
#pragma unroll
        for (int ni = 0; ni < 4; ++ni) {
          int row = wm + mi * 16 + lr;                 // 0..63 (two waves cover all)
          int cp = ((ni * 4 + kg) ^ lr) * 4;           // 16-chunk swizzle, key lr
          *(f32x4*)(buf + row * 64 + cp) = acc[mi][ni];
        }
    }
    __syncthreads();
#pragma unroll
    for (int i = 0; i < 4; ++i) {
      int row = i * 16 + (tid >> 4);
      int lc = tid & 15;
      float4 v = *(const float4*)(buf + row * 64 + ((lc ^ (row & 15)) * 4));
      *(float4*)(C + (size_t)(bm + row) * 1024 + bn + hc * 64 + lc * 4) = v;
    }
  }
}

// ---------------- MFMA flash attention v17: v14 body + balanced qi map ONLY -------
// Single-variable isolation: R13/R16 bundled {balanced map, diag-hoist, QK-setprio}
// and regressed ~3 us e2e, but their per-kernel counters showed attn FASTER.
// This round: champion v14 body byte-for-byte (per-round masking, PV-only setprio,
// VALU lsum) with ONLY the block->(qi,bh) map changed to the stride-256-balanced
// version: qi = {31-w, w, 16+w, 15-w}[idx>>8], w=(idx&255)>>5. With all 1024
// blocks resident (4/CU x 256 CU), per-CU round-sums become exactly 62 (heavy-
// first: 48..76 -> makespan 76). bh map unchanged (XCD-grouped).
__global__ __launch_bounds__(256, 4) void attn_mfma_kernel(const u16* __restrict__ qk,
                                                           const u16* __restrict__ vt,
                                                           u16* __restrict__ out) {
  __shared__ __attribute__((aligned(16))) u16 sK[2][64 * 64];  // [j][d] swizzled
  __shared__ __attribute__((aligned(16))) u16 sV[2][64 * 64];  // [d][j] swizzled

  const int tid = threadIdx.x;
  const int wave = tid >> 6;
  const int lane = tid & 63;
  const int l31 = lane & 31;
  const int hi = lane >> 5;
  const int qh = wave & 1;   // q half (32 rows of the 64-q tile)
  const int jh = wave >> 1;  // j half (32 cols of each 64-j tile)

  const int idx = blockIdx.x;
  const int kq = idx >> 8;       // 0..3
  const int ci = idx & 255;
  const int w = ci >> 5;         // 0..7
  const int qi = (kq == 0) ? (31 - w) : (kq == 1) ? w : (kq == 2) ? (16 + w) : (15 - w);
  const int bh = (ci & 7) * 4 + ((ci >> 3) & 3);  // XCD-local bh grouping
  const int b = bh >> 4, h = bh & 15;
  const int q0 = qi * 64;

  const u16* qbase = qk + (size_t)b * 2048 * 2048 + h * 64;
  const u16* kbase = qbase + 1024;
  const u16* vbase = vt + (size_t)bh * 64 * 2048;
  u16* obase = out + (size_t)b * 2048 * 1024 + h * 64;

  const int sra = wave * 16 + (lane >> 3);
  const int srb = sra + 8;
  const int sc = lane & 7;
  const u32 koffA = (u32)sra * 2048 + (u32)((sc ^ (sra & 7)) * 8);
  const u32 koffB = (u32)srb * 2048 + (u32)((sc ^ (srb & 7)) * 8);
  const u32 ldsA = (wave * 2 + 0) * 512;
  const u32 ldsB = (wave * 2 + 1) * 512;

  const int qcol = q0 + qh * 32 + l31;
  bf16x8 qf[4];
  {
    const u16* qrow = qbase + (size_t)qcol * 2048;
#pragma unroll
    for (int s = 0; s < 4; ++s) qf[s] = *(const bf16x8*)(qrow + s * 16 + hi * 8);
  }

  f32x16 oacc[2];
#pragma unroll
  for (int i = 0; i < 16; ++i) { oacc[0][i] = 0.f; oacc[1][i] = 0.f; }
  float ls = 0.f;

  const int nrounds = qi + 1;
  gld_lds16(kbase + koffA, sK[0] + ldsA);
  gld_lds16(kbase + koffB, sK[0] + ldsB);
  gld_lds16(vbase + koffA, sV[0] + ldsA);
  gld_lds16(vbase + koffB, sV[0] + ldsB);
  __syncthreads();

  for (int t = 0; t < nrounds; ++t) {
    if (t + 1 < nrounds) {
      int j1 = (t + 1) * 64;
      u16* dK = sK[(t + 1) & 1];
      u16* dV = sV[(t + 1) & 1];
      gld_lds16(kbase + (size_t)j1 * 2048 + koffA, dK + ldsA);
      gld_lds16(kbase + (size_t)j1 * 2048 + koffB, dK + ldsB);
      gld_lds16(vbase + j1 + koffA, dV + ldsA);
      gld_lds16(vbase + j1 + koffB, dV + ldsB);
    }
    const u16* sKb = sK[t & 1];
    const u16* sVb = sV[t & 1];
    const bool diag = (t == qi);

    f32x16 c;
#pragma unroll
    for (int i = 0; i < 16; ++i) c[i] = 0.f;
#pragma unroll
    for (int s = 0; s < 4; ++s) {
      const u32 row = (u32)(jh * 32 + l31);
      bf16x8 kf = *(const bf16x8*)(sKb + row * 64 + (((2 * s + hi) ^ (row & 7)) * 8));
      c = __builtin_amdgcn_mfma_f32_32x32x16_bf16(kf, qf[s], c, 0, 0, 0);
    }
    float p[16];
    const int qrel = qh * 32 + l31;
#pragma unroll
    for (int r = 0; r < 16; ++r) {
      int joff = jh * 32 + (r & 3) + 8 * (r >> 2) + 4 * hi;
      float e = exp2f(c[r]);
      p[r] = (!diag || (joff <= qrel)) ? e : 0.f;
    }
    {
      float s0 = (p[0] + p[1]) + (p[2] + p[3]);
      float s1 = (p[4] + p[5]) + (p[6] + p[7]);
      float s2 = (p[8] + p[9]) + (p[10] + p[11]);
      float s3 = (p[12] + p[13]) + (p[14] + p[15]);
      ls += (s0 + s1) + (s2 + s3);
    }
    u32 c01 = pkf16(p[0], p[1]),   c23 = pkf16(p[2], p[3]);
    u32 c45 = pkf16(p[4], p[5]),   c67 = pkf16(p[6], p[7]);
    u32 c89 = pkf16(p[8], p[9]),   cab = pkf16(p[10], p[11]);
    u32 ccd = pkf16(p[12], p[13]), cef = pkf16(p[14], p[15]);
    asm volatile("v_permlane32_swap_b32 %0, %1" : "+v"(c01), "+v"(c45));
    asm volatile("v_permlane32_swap_b32 %0, %1" : "+v"(c23), "+v"(c67));
    asm volatile("v_permlane32_swap_b32 %0, %1" : "+v"(c89), "+v"(ccd));
    asm volatile("v_permlane32_swap_b32 %0, %1" : "+v"(cab), "+v"(cef));
    u32x4 w0 = {c01, c23, c45, c67};
    u32x4 w1 = {c89, cab, ccd, cef};
    f16x8 pa0 = __builtin_bit_cast(f16x8, w0);
    f16x8 pa1 = __builtin_bit_cast(f16x8, w1);

    __builtin_amdgcn_s_setprio(1);
#pragma unroll
    for (int dh = 0; dh < 2; ++dh) {
      const u32 row = (u32)(dh * 32 + l31);
#pragma unroll
      for (int s2 = 0; s2 < 2; ++s2) {
        f16x8 vf = *(const f16x8*)(sVb + row * 64 +
                                   (((4 * jh + 2 * s2 + hi) ^ (row & 7)) * 8));
        oacc[dh] = __builtin_amdgcn_mfma_f32_32x32x16_f16(
            vf, (s2 == 0) ? pa0 : pa1, oacc[dh], 0, 0, 0);
      }
    }
    __builtin_amdgcn_s_setprio(0);
    __syncthreads();
  }

  ls += __shfl_xor(ls, 32);

  float* obuf = (float*)sK;  // [64 q][64 d] f32 = 16 KB, chunk-swizzled by q&15
  float* lbuf = (float*)sV;  // 64 f32
  const int q = qh * 32 + l31;
  if (jh == 1) {
#pragma unroll
    for (int dh = 0; dh < 2; ++dh)
#pragma unroll
      for (int g = 0; g < 4; ++g) {
        int ch = dh * 8 + g * 2 + hi;
        f32x4 wv = {oacc[dh][4 * g + 0], oacc[dh][4 * g + 1],
                    oacc[dh][4 * g + 2], oacc[dh][4 * g + 3]};
        *(f32x4*)(obuf + q * 64 + ((ch ^ (q & 15)) * 4)) = wv;
      }
    if (hi == 0) lbuf[q] = ls;
  }
  __syncthreads();
  if (jh == 0) {
    float inv = 1.0f / (ls + lbuf[q]);
    u16* orow = obase + (size_t)qcol * 1024;
#pragma unroll
    for (int dh = 0; dh < 2; ++dh)
#pragma unroll
      for (int g = 0; g < 4; ++g) {
        int ch = dh * 8 + g * 2 + hi;
        f32x4 po = *(const f32x4*)(obuf + q * 64 + ((ch ^ (q & 15)) * 4));
        float o0 = (oacc[dh][4 * g + 0] + po[0]) * inv;
        float o1 = (oacc[dh][4 * g + 1] + po[1]) * inv;
        float o2 = (oacc[dh][4 * g + 2] + po[2]) * inv;
        float o3 = (oacc[dh][4 * g + 3] + po[3]) * inv;
        *(uint2*)(orow + dh * 32 + g * 8 + hi * 4) = make_uint2(pack2(o0, o1), pack2(o2, o3));
      }
  }
}

// ---------------- launch ----------------
extern "C" void kernel_launch(void* const* d_in, const int* in_sizes, int n_in,
                              void* d_out, int out_size, void* d_ws, size_t ws_size,
                              hipStream_t stream) {
  const float* x = (const float*)d_in[0];      // [2,2048,1024]
  const float* w_qkv = (const float*)d_in[1];  // [1024,3072]
  const float* w_out = (const float*)d_in[2];  // [1024,1024]
  float* out = (float*)d_out;                  // [2,2048,1024] fp32

  char* ws = (char*)d_ws;
  u16* xb    = (u16*)(ws);                //  8 MB: x bf16 [4096,1024]
  u16* wqkvT = (u16*)(ws + (8u << 20));   //  6 MB: w_qkv^T bf16 [3072,1024]
  u16* woutT = (u16*)(ws + (14u << 20));  //  2 MB: w_out^T bf16 [1024,1024]
  u16* qkb   = (u16*)(ws + (16u << 20));  // 16 MB: q|k bf16 [4096,2048]
  u16* vtb   = (u16*)(ws + (32u << 20));  //  8 MB: V^T f16 [32,64,2048]
  u16* attn  = (u16*)(ws + (40u << 20));  //  8 MB: attn out bf16 [4096,1024]

  prepass_kernel<<<5120, 256, 0, stream>>>(x, w_qkv, w_out, xb, wqkvT, woutT);

  gemm_qkv128_kernel<<<512, 512, 0, stream>>>(xb, wqkvT, qkb, vtb);

  attn_mfma_kernel<<<1024, 256, 0, stream>>>(qkb, vtb, attn);

  gemm_out_kernel<<<512, 256, 0, stream>>>(attn, woutT, out);
}